// Round 11
// baseline (89.333 us; speedup 1.0000x reference)
//
#include <hip/hip_runtime.h>

#define CH      256
#define HH      128
#define WW      128
#define HWPIX   (HH * WW)       // 16384
#define NTHR    512
#define NGRP    8               // channel groups (= waves per block)
#define CPG     32              // channels per thread
#define TILE_PX 256             // 2 rows per block

typedef float nativef4 __attribute__((ext_vector_type(4)));

// R10 + 1KB-contiguous wave accesses: block = 2 rows x all 256 channels,
// q=tid&63 so each wave's load AND nt-store is a single 1KB segment.
// Raster: R8-proven strided loop, scalar bbox loads; 2-row/4-word bitmask.
__global__ __launch_bounds__(NTHR, 2) void k_fused(
    const float* __restrict__ x,
    const float* __restrict__ bboxes,
    const int*   __restrict__ batch_idx,
    float*       __restrict__ out,
    int N)
{
    const int b    = blockIdx.x >> 6;          // 64 two-row tiles per image
    const int tile = blockIdx.x & 63;
    const int pix0 = tile * TILE_PX;
    const int r0   = tile * 2;                 // first row of tile

    const int q = threadIdx.x & 63;            // quad: tile-local px 4q..4q+3
    const int g = threadIdx.x >> 6;            // 0..7: channel group (= wave)

    const size_t base = ((size_t)b * CH + (size_t)g * CPG) * HWPIX
                      + pix0 + 4 * q;
    const float4* __restrict__ xq = (const float4*)(x + base);
    const size_t pstride = HWPIX / 4;

    __shared__ unsigned long long smask[4];    // [2*row_loc + colword]
    __shared__ float4 part[NGRP][64];          // 8 KB

    if (threadIdx.x < 4) smask[threadIdx.x] = 0ull;
    __syncthreads();

    // ---- issue all 32 loads (1KB contiguous per wave); keep live ----
    float4 v[CPG];
    #pragma unroll
    for (int j = 0; j < CPG; ++j)
        v[j] = xq[(size_t)j * pstride];

    // ---- raster into 4-word bitmask (overlaps load latency) ----
    for (int n = threadIdx.x; n < N; n += NTHR) {
        if (batch_idx[n] != b) continue;
        const float xc = bboxes[4 * n + 0];
        const float yc = bboxes[4 * n + 1];
        const float bw = bboxes[4 * n + 2];
        const float bh = bboxes[4 * n + 3];
        // match jnp.trunc(...).astype(int32) then max/min clamps exactly
        const int x1 = max(0,      (int)truncf((xc - bw * 0.5f) * (float)WW));
        const int y1 = max(0,      (int)truncf((yc - bh * 0.5f) * (float)HH));
        const int x2 = min(WW - 1, (int)truncf((xc + bw * 0.5f) * (float)WW));
        const int y2 = min(HH - 1, (int)truncf((yc + bh * 0.5f) * (float)HH));
        if (!(x2 > x1 && y2 > y1)) continue;
        if (y2 < r0 || y1 > r0 + 1) continue;

        // column masks for word 0 (cols 0..63) and word 1 (cols 64..127)
        unsigned long long m0 = 0ull, m1 = 0ull;
        {
            const int a0 = x1;                 // >= 0 by clamp
            const int b0 = min(x2, 63);
            if (a0 <= b0) {
                const unsigned long long hm =
                    (b0 == 63) ? ~0ull : ((1ull << (b0 + 1)) - 1ull);
                const unsigned long long lm = (1ull << a0) - 1ull;
                m0 = hm & ~lm;
            }
        }
        {
            const int a0 = max(x1 - 64, 0);
            const int b0 = x2 - 64;            // x2 <= 127
            if (b0 >= 0 && a0 <= b0) {
                const unsigned long long hm =
                    (b0 == 63) ? ~0ull : ((1ull << (b0 + 1)) - 1ull);
                const unsigned long long lm = (1ull << a0) - 1ull;
                m1 = hm & ~lm;
            }
        }
        if (r0 >= y1 && r0 <= y2) {
            if (m0) atomicOr(&smask[0], m0);
            if (m1) atomicOr(&smask[1], m1);
        }
        if (r0 + 1 >= y1 && r0 + 1 <= y2) {
            if (m0) atomicOr(&smask[2], m0);
            if (m1) atomicOr(&smask[3], m1);
        }
    }

    // ---- per-thread partial sum over its 32 channels ----
    float4 s0 = make_float4(0.f, 0.f, 0.f, 0.f);
    float4 s1 = make_float4(0.f, 0.f, 0.f, 0.f);
    #pragma unroll
    for (int j = 0; j < CPG; j += 2) {
        s0.x += v[j].x;     s0.y += v[j].y;     s0.z += v[j].z;     s0.w += v[j].w;
        s1.x += v[j + 1].x; s1.y += v[j + 1].y; s1.z += v[j + 1].z; s1.w += v[j + 1].w;
    }
    s0.x += s1.x; s0.y += s1.y; s0.z += s1.z; s0.w += s1.w;

    part[g][q] = s0;
    __syncthreads();                           // also covers raster completion

    float4 tot = make_float4(0.f, 0.f, 0.f, 0.f);
    #pragma unroll
    for (int gg = 0; gg < NGRP; ++gg) {
        const float4 p = part[gg][q];
        tot.x += p.x; tot.y += p.y; tot.z += p.z; tot.w += p.w;
    }

    // ---- masked addend: row_loc = q>>5, colword = (q>>4)&1 ----
    const unsigned long long m = smask[2 * (q >> 5) + ((q >> 4) & 1)];
    const int bit0 = (4 * q) & 63;
    const float inv = 1.0f / (float)CH;
    float4 a;
    a.x = ((m >> (bit0 + 0)) & 1ull) ? tot.x * inv : 0.0f;
    a.y = ((m >> (bit0 + 1)) & 1ull) ? tot.y * inv : 0.0f;
    a.z = ((m >> (bit0 + 2)) & 1ull) ? tot.z * inv : 0.0f;
    a.w = ((m >> (bit0 + 3)) & 1ull) ? tot.w * inv : 0.0f;

    // ---- nt-store out = x + addend (1KB contiguous per wave) ----
    nativef4* __restrict__ oq = (nativef4*)(out + base);
    #pragma unroll
    for (int j = 0; j < CPG; ++j) {
        const float4 vv = v[j];
        nativef4 o;
        o.x = vv.x + a.x; o.y = vv.y + a.y; o.z = vv.z + a.z; o.w = vv.w + a.w;
        __builtin_nontemporal_store(o, &oq[(size_t)j * pstride]);
    }
}

extern "C" void kernel_launch(void* const* d_in, const int* in_sizes, int n_in,
                              void* d_out, int out_size, void* d_ws, size_t ws_size,
                              hipStream_t stream)
{
    const float* x         = (const float*)d_in[0];
    const float* bboxes    = (const float*)d_in[1];
    const int*   batch_idx = (const int*)d_in[2];
    float*       out       = (float*)d_out;

    const int N = in_sizes[1] / 4;             // 320 boxes
    const int B = 16;

    const int blocks = B * (HWPIX / TILE_PX);  // 1024
    k_fused<<<blocks, NTHR, 0, stream>>>(x, bboxes, batch_idx, out, N);
}

// Round 12
// 81.614 us; speedup vs baseline: 1.0946x; 1.0946x over previous
//
#include <hip/hip_runtime.h>

#define CH      256
#define HH      128
#define WW      128
#define HWPIX   (HH * WW)       // 16384
#define NTHR    512
#define NGRP    32              // channel groups
#define CPG     8               // channels per thread (low VGPR -> high occupancy)
#define QUADS   16              // pixel quads per half-row tile (64 px)

typedef float nativef4 __attribute__((ext_vector_type(4)));

// R10 structure at doubled occupancy: half-row tile, CPG=8 so v[8] fits the
// 64-VGPR budget of __launch_bounds__(512,8) -> up to 32 waves/CU to fill
// the bulk-synchronous phase gaps. nt-stores keep out from polluting L3.
__global__ __launch_bounds__(NTHR, 8) void k_fused(
    const float* __restrict__ x,
    const float* __restrict__ bboxes,
    const int*   __restrict__ batch_idx,
    float*       __restrict__ out,
    int N)
{
    const int b     = blockIdx.x >> 8;         // 256 half-row tiles per image
    const int tile  = blockIdx.x & 255;
    const int r     = tile >> 1;               // row
    const int wbase = (tile & 1) << 6;         // 0 or 64: column window

    const int q = threadIdx.x & (QUADS - 1);   // 0..15: quad (cols wbase+4q..+3)
    const int g = threadIdx.x >> 4;            // 0..31: channel group

    const size_t base = ((size_t)b * CH + (size_t)g * CPG) * HWPIX
                      + (size_t)r * WW + wbase + 4 * q;
    const float4* __restrict__ xq = (const float4*)(x + base);
    const size_t pstride = HWPIX / 4;

    __shared__ unsigned long long smask;       // single u64: this half-row
    __shared__ float4 part[NGRP][QUADS];       // 8 KB

    if (threadIdx.x == 0) smask = 0ull;
    __syncthreads();

    // ---- issue all 8 loads; keep live in VGPRs ----
    float4 v[CPG];
    #pragma unroll
    for (int j = 0; j < CPG; ++j)
        v[j] = xq[(size_t)j * pstride];

    // ---- raster into the u64 (overlaps load latency); R4-proven algebra ----
    for (int n = threadIdx.x; n < N; n += NTHR) {
        if (batch_idx[n] != b) continue;
        const float xc = bboxes[4 * n + 0];
        const float yc = bboxes[4 * n + 1];
        const float bw = bboxes[4 * n + 2];
        const float bh = bboxes[4 * n + 3];
        // match jnp.trunc(...).astype(int32) then max/min clamps exactly
        const int x1 = max(0,      (int)truncf((xc - bw * 0.5f) * (float)WW));
        const int y1 = max(0,      (int)truncf((yc - bh * 0.5f) * (float)HH));
        const int x2 = min(WW - 1, (int)truncf((xc + bw * 0.5f) * (float)WW));
        const int y2 = min(HH - 1, (int)truncf((yc + bh * 0.5f) * (float)HH));
        if (!(x2 > x1 && y2 > y1)) continue;
        if (r < y1 || r > y2) continue;
        const int a0 = max(x1 - wbase, 0);
        const int b0 = min(x2 - wbase, 63);
        if (a0 > b0) continue;
        const unsigned long long hm =
            (b0 == 63) ? ~0ull : ((1ull << (b0 + 1)) - 1ull);
        const unsigned long long lm = (1ull << a0) - 1ull;
        atomicOr(&smask, hm & ~lm);
    }

    // ---- per-thread partial sum over its 8 channels ----
    float4 ps = make_float4(0.f, 0.f, 0.f, 0.f);
    #pragma unroll
    for (int j = 0; j < CPG; ++j) {
        ps.x += v[j].x; ps.y += v[j].y; ps.z += v[j].z; ps.w += v[j].w;
    }
    part[g][q] = ps;
    __syncthreads();                           // also covers raster completion

    float4 tot = make_float4(0.f, 0.f, 0.f, 0.f);
    #pragma unroll
    for (int gg = 0; gg < NGRP; ++gg) {
        const float4 p = part[gg][q];
        tot.x += p.x; tot.y += p.y; tot.z += p.z; tot.w += p.w;
    }

    // ---- masked addend for this lane's quad ----
    const unsigned long long m = smask;
    const int bit0 = 4 * q;                    // q <= 15 -> bits 0..63
    const float inv = 1.0f / (float)CH;
    float4 a;
    a.x = ((m >> (bit0 + 0)) & 1ull) ? tot.x * inv : 0.0f;
    a.y = ((m >> (bit0 + 1)) & 1ull) ? tot.y * inv : 0.0f;
    a.z = ((m >> (bit0 + 2)) & 1ull) ? tot.z * inv : 0.0f;
    a.w = ((m >> (bit0 + 3)) & 1ull) ? tot.w * inv : 0.0f;

    // ---- nt-store out = x + addend ----
    nativef4* __restrict__ oq = (nativef4*)(out + base);
    #pragma unroll
    for (int j = 0; j < CPG; ++j) {
        const float4 vv = v[j];
        nativef4 o;
        o.x = vv.x + a.x; o.y = vv.y + a.y; o.z = vv.z + a.z; o.w = vv.w + a.w;
        __builtin_nontemporal_store(o, &oq[(size_t)j * pstride]);
    }
}

extern "C" void kernel_launch(void* const* d_in, const int* in_sizes, int n_in,
                              void* d_out, int out_size, void* d_ws, size_t ws_size,
                              hipStream_t stream)
{
    const float* x         = (const float*)d_in[0];
    const float* bboxes    = (const float*)d_in[1];
    const int*   batch_idx = (const int*)d_in[2];
    float*       out       = (float*)d_out;

    const int N = in_sizes[1] / 4;             // 320 boxes
    const int B = 16;

    const int blocks = B * 256;                // 4096 half-row tiles
    k_fused<<<blocks, NTHR, 0, stream>>>(x, bboxes, batch_idx, out, N);
}